// Round 3
// baseline (550.485 us; speedup 1.0000x reference)
//
#include <hip/hip_runtime.h>
#include <stdint.h>
#include <math.h>

// Problem constants
#define N_SEQ 4096
#define EDIM  2048
#define NH    16
#define HD    128

typedef __attribute__((ext_vector_type(8))) short bf16x8;
typedef __attribute__((ext_vector_type(4))) float f32x4;

#define AS1 __attribute__((address_space(1)))
#define AS3 __attribute__((address_space(3)))

__device__ __forceinline__ void gll16(const unsigned short* g, unsigned short* l) {
    __builtin_amdgcn_global_load_lds((const AS1 unsigned int*)g,
                                     (AS3 unsigned int*)l, 16, 0, 0);
}

__device__ __forceinline__ unsigned short f2bf(float f) {
    union { float f; unsigned u; } v; v.f = f;
    unsigned r = v.u + 0x7FFFu + ((v.u >> 16) & 1u);
    return (unsigned short)(r >> 16);
}
__device__ __forceinline__ float bf2f(unsigned short h) {
    union { unsigned u; float f; } v; v.u = ((unsigned)h) << 16;
    return v.f;
}

// ---------------------------------------------------------------- convert x
__global__ void k_convert_x(const float* __restrict__ x,
                            unsigned short* __restrict__ xb, int n4) {
    int i = blockIdx.x * blockDim.x + threadIdx.x;
    int stride = gridDim.x * blockDim.x;
    for (; i < n4; i += stride) {
        float4 v = ((const float4*)x)[i];
        ushort4 o;
        o.x = f2bf(v.x); o.y = f2bf(v.y); o.z = f2bf(v.z); o.w = f2bf(v.w);
        ((ushort4*)xb)[i] = o;
    }
}

// ---------------------------------------------- transpose f32 (RxC) -> bf16 (CxR)
__global__ void k_transpose_f32_bf16(const float* __restrict__ in,
                                     unsigned short* __restrict__ out,
                                     int R, int C) {
    __shared__ unsigned short Ls[64][68];
    const int c0 = blockIdx.x * 64, r0 = blockIdx.y * 64;
    const int t = threadIdx.x;
    #pragma unroll
    for (int i = 0; i < 4; ++i) {
        int ch = i * 256 + t;              // 1024 float4 chunks
        int r = ch >> 4, c4 = (ch & 15) * 4;
        float4 v = *(const float4*)&in[(size_t)(r0 + r) * C + c0 + c4];
        ushort4 o;
        o.x = f2bf(v.x); o.y = f2bf(v.y); o.z = f2bf(v.z); o.w = f2bf(v.w);
        *(ushort4*)&Ls[r][c4] = o;
    }
    __syncthreads();
    #pragma unroll
    for (int i = 0; i < 2; ++i) {
        int ch = i * 256 + t;              // 512 chunks of 8 bf16
        int rr = ch >> 3, c8 = (ch & 7) * 8;
        unsigned short vals[8];
        #pragma unroll
        for (int j = 0; j < 8; ++j) vals[j] = Ls[c8 + j][rr];
        uint4 pk;
        pk.x = (unsigned)vals[0] | ((unsigned)vals[1] << 16);
        pk.y = (unsigned)vals[2] | ((unsigned)vals[3] << 16);
        pk.z = (unsigned)vals[4] | ((unsigned)vals[5] << 16);
        pk.w = (unsigned)vals[6] | ((unsigned)vals[7] << 16);
        *(uint4*)&out[(size_t)(c0 + rr) * R + r0 + c8] = pk;
    }
}

// ---------------------------------------------------------------- bt GEMM
// C[M,N] = A[M,K] * Bt[N,K]^T  (bf16 in, f32 acc, bf16 or f32 out)
template<int F32OUT>
__launch_bounds__(256, 2)
__global__ void k_gemm_bt(const unsigned short* __restrict__ A,
                          const unsigned short* __restrict__ Bt,
                          void* __restrict__ C,
                          int M, int N, int K) {
    __shared__ unsigned short sh[2 * 128 * 64];   // As | Bs, linear [128][64]
    unsigned short* As = sh;
    unsigned short* Bs = sh + 128 * 64;

    const int t = threadIdx.x;
    const int wave = t >> 6, lane = t & 63;
    const int wm = wave >> 1, wn = wave & 1;
    const int lg = lane >> 4, lr = lane & 15;

    // XCD-aware bijective swizzle (nwg % 8 == 0 for all our grids)
    const int nbx = gridDim.x;
    const int nwg = nbx * gridDim.y;
    int bid = blockIdx.y * nbx + blockIdx.x;
    int swz = (bid & 7) * (nwg >> 3) + (bid >> 3);
    const int m0 = (swz / nbx) * 128;
    const int n0 = (swz % nbx) * 128;

    const unsigned short* aptr = A  + (size_t)m0 * K;
    const unsigned short* bptr = Bt + (size_t)n0 * K;

    f32x4 acc[4][4];
    #pragma unroll
    for (int i = 0; i < 4; ++i)
        #pragma unroll
        for (int j = 0; j < 4; ++j) acc[i][j] = f32x4{0.f, 0.f, 0.f, 0.f};

    // per-thread staging geometry (loop-invariant)
    int schr[4], srow[4], scb[4];
    #pragma unroll
    for (int i = 0; i < 4; ++i) {
        int ch = (i * 4 + wave) * 64 + lane;   // 0..1023, wave-uniform base + lane
        schr[i] = ch;
        srow[i] = ch >> 3;
        scb[i]  = (ch & 7) ^ ((ch >> 3) & 7);  // inverse-swizzled source col-block
    }

    const int nkb = K >> 6;
    for (int kb = 0; kb < nkb; ++kb) {
        __syncthreads();   // previous iter's ds_reads done before overwrite
        #pragma unroll
        for (int i = 0; i < 4; ++i) {
            const size_t goff = (size_t)srow[i] * K + (size_t)kb * 64 + scb[i] * 8;
            gll16(&aptr[goff], &As[schr[i] * 8]);
            gll16(&bptr[goff], &Bs[schr[i] * 8]);
        }
        __syncthreads();   // drains vmcnt+lgkm (compiler-inserted before barrier)

        #pragma unroll
        for (int kk = 0; kk < 2; ++kk) {
            bf16x8 af[4], bf[4];
            const int cbx = ((kk * 4 + lg) ^ (lr & 7)) * 8;  // swizzled read col
            #pragma unroll
            for (int i = 0; i < 4; ++i) {
                af[i] = *(const bf16x8*)&As[(wm * 64 + i * 16 + lr) * 64 + cbx];
                bf[i] = *(const bf16x8*)&Bs[(wn * 64 + i * 16 + lr) * 64 + cbx];
            }
            #pragma unroll
            for (int i = 0; i < 4; ++i)
                #pragma unroll
                for (int j = 0; j < 4; ++j)
                    acc[i][j] = __builtin_amdgcn_mfma_f32_16x16x32_bf16(af[i], bf[j], acc[i][j], 0, 0, 0);
        }
    }

    if (F32OUT) {
        #pragma unroll
        for (int i = 0; i < 4; ++i) {
            int row0 = m0 + wm * 64 + i * 16 + lg * 4;
            #pragma unroll
            for (int j = 0; j < 4; ++j) {
                int col = n0 + wn * 64 + j * 16 + lr;
                #pragma unroll
                for (int r = 0; r < 4; ++r)
                    ((float*)C)[(size_t)(row0 + r) * N + col] = acc[i][j][r];
            }
        }
    } else {
        // stage bf16 C-tile in LDS, write out coalesced uint4 rows
        __syncthreads();
        unsigned short* Cs = sh;     // [128][128]
        #pragma unroll
        for (int i = 0; i < 4; ++i) {
            #pragma unroll
            for (int j = 0; j < 4; ++j) {
                int col = wn * 64 + j * 16 + lr;
                #pragma unroll
                for (int r = 0; r < 4; ++r)
                    Cs[(wm * 64 + i * 16 + lg * 4 + r) * 128 + col] = f2bf(acc[i][j][r]);
            }
        }
        __syncthreads();
        #pragma unroll
        for (int i = 0; i < 8; ++i) {
            int ch = i * 256 + t;             // 2048 chunks of 8 shorts
            int row = ch >> 4, c8 = (ch & 15) * 8;
            *(uint4*)&((unsigned short*)C)[(size_t)(m0 + row) * N + n0 + c8] =
                *(const uint4*)&Cs[row * 128 + c8];
        }
    }
}

// ------------------------------------------------------- RoPE + LayerNorm (q,k)
__global__ void k_ropeln(const unsigned short* __restrict__ proj,
                         const float* __restrict__ ln_scale,
                         const float* __restrict__ ln_bias,
                         unsigned short* __restrict__ Qh,
                         unsigned short* __restrict__ Kh) {
    const int n = blockIdx.x;
    const int wave = threadIdx.x >> 6, lane = threadIdx.x & 63;
    float inv = expf(-((float)(2 * lane) / 128.0f) * 9.210340371976184f);
    float ang = (float)n * inv;
    float c = cosf(ang), s = sinf(ang);
    const float sc1 = ln_scale[lane], sc2 = ln_scale[lane + 64];
    const float b1 = ln_bias[lane],  b2 = ln_bias[lane + 64];

    for (int r = wave; r < 32; r += 4) {
        int h = r >> 1, qk = r & 1;
        const unsigned short* src = proj + (size_t)n * (3 * EDIM) + qk * EDIM + h * HD;
        float x1 = bf2f(src[lane]), x2 = bf2f(src[lane + 64]);
        float o1 = x1 * c - x2 * s;
        float o2 = x1 * s + x2 * c;
        float sum = o1 + o2, sq = o1 * o1 + o2 * o2;
        #pragma unroll
        for (int d = 1; d < 64; d <<= 1) {
            sum += __shfl_xor(sum, d);
            sq  += __shfl_xor(sq, d);
        }
        float mean = sum * (1.0f / 128.0f);
        float var = sq * (1.0f / 128.0f) - mean * mean;
        float rstd = rsqrtf(var + 1e-5f);
        float y1 = (o1 - mean) * rstd * sc1 + b1;
        float y2 = (o2 - mean) * rstd * sc2 + b2;
        unsigned short* dst = (qk ? Kh : Qh) + ((size_t)h * N_SEQ + n) * HD;
        dst[lane]      = f2bf(y1);
        dst[lane + 64] = f2bf(y2);
    }
}

// ---------------------------------------------------- V transpose: [n][d] -> [d][n]
__global__ void k_vtrans(const unsigned short* __restrict__ proj,
                         unsigned short* __restrict__ Vt) {
    __shared__ unsigned short Ls[64][136];
    const int h = blockIdx.y;
    const int n0 = blockIdx.x * 64;
    const int t = threadIdx.x;
    #pragma unroll
    for (int i = 0; i < 4; ++i) {
        int ch = i * 256 + t;
        int r = ch >> 4, d0 = (ch & 15) * 8;
        uint4 v = *(const uint4*)&proj[(size_t)(n0 + r) * (3 * EDIM) + 2 * EDIM + h * HD + d0];
        *(uint4*)&Ls[r][d0] = v;
    }
    __syncthreads();
    #pragma unroll
    for (int i = 0; i < 4; ++i) {
        int ch = i * 256 + t;
        int d = ch >> 3, nb = (ch & 7) * 8;
        unsigned short vals[8];
        #pragma unroll
        for (int j = 0; j < 8; ++j) vals[j] = Ls[nb + j][d];
        uint4 pk;
        pk.x = (unsigned)vals[0] | ((unsigned)vals[1] << 16);
        pk.y = (unsigned)vals[2] | ((unsigned)vals[3] << 16);
        pk.z = (unsigned)vals[4] | ((unsigned)vals[5] << 16);
        pk.w = (unsigned)vals[6] | ((unsigned)vals[7] << 16);
        *(uint4*)&Vt[((size_t)h * HD + d) * N_SEQ + n0 + nb] = pk;
    }
}

// ------------------------------------------------------- polynomial attention
// Qh,Kh: [NH][N_SEQ][HD], Vt: [NH][HD][N_SEQ]. O: [N_SEQ][EDIM] bf16.
// Balanced 1-D grid: slot s in batch 0 -> qb=31-i (heavy, dispatched first),
// batch 1 -> qb=i (light), so every CU's 2 resident blocks total 66 iters.
// LDS: XOR-swizzled unpadded tiles (48 KB): Ks[64][128], Vts[128][64], Ps[128][64].
__launch_bounds__(256, 2)
__global__ void k_attn(const unsigned short* __restrict__ Qh,
                       const unsigned short* __restrict__ Kh,
                       const unsigned short* __restrict__ Vt,
                       unsigned short* __restrict__ O) {
    __shared__ unsigned short pool[3 * 8192];
    unsigned short* Ks  = pool;            // [64][128], 16 chunks/row, swz low3
    unsigned short* Vts = pool + 8192;     // [128][64] (V^T), 8 chunks/row
    unsigned short* Ps  = pool + 16384;    // [128][64], 8 chunks/row

    const int t = threadIdx.x;
    const int wave = t >> 6, lane = t & 63;
    const int wm = wave >> 1, wn = wave & 1;
    const int lg = lane >> 4, lr = lane & 15;

    const int s = blockIdx.x & 255;
    const int batch = blockIdx.x >> 8;
    const int h = s >> 4;          // same-head slots co-located per XCD
    const int ii = s & 15;
    const int qb = batch ? ii : (31 - ii);
    const int q0 = qb * 128;

    // Q fragments in registers (wave's 64 queries x 128 d)
    bf16x8 qf[4][4];
    #pragma unroll
    for (int mi = 0; mi < 4; ++mi)
        #pragma unroll
        for (int kk = 0; kk < 4; ++kk)
            qf[mi][kk] = *(const bf16x8*)&Qh[((size_t)h * N_SEQ + q0 + wm * 64 + mi * 16 + lr) * HD + kk * 32 + lg * 8];

    f32x4 acc[4][4];
    #pragma unroll
    for (int i = 0; i < 4; ++i)
        #pragma unroll
        for (int j = 0; j < 4; ++j) acc[i][j] = f32x4{0.f, 0.f, 0.f, 0.f};
    f32x4 accd[4];
    #pragma unroll
    for (int i = 0; i < 4; ++i) accd[i] = f32x4{0.f, 0.f, 0.f, 0.f};

    // ones B-fragment: row-sum lands in output col 0
    bf16x8 onesf;
    {
        short ov = (lr == 0) ? (short)0x3F80 : (short)0;
        #pragma unroll
        for (int j = 0; j < 8; ++j) onesf[j] = ov;
    }

    const int nkb = 2 * qb + 2;
    for (int kb = 0; kb < nkb; ++kb) {
        const int k0 = kb * 64;
        // issue K/V loads early (reg-staged)
        uint4 kr[4], vr[4];
        #pragma unroll
        for (int i = 0; i < 4; ++i) {
            int ch = i * 256 + t;
            { int r = ch >> 4, c = ch & 15;
              kr[i] = *(const uint4*)&Kh[((size_t)h * N_SEQ + k0 + r) * HD + c * 8]; }
            { int d = ch >> 3, c2 = ch & 7;
              vr[i] = *(const uint4*)&Vt[((size_t)h * HD + d) * N_SEQ + k0 + c2 * 8]; }
        }
        __syncthreads();   // previous iter's LDS reads done
        #pragma unroll
        for (int i = 0; i < 4; ++i) {
            int ch = i * 256 + t;
            { int r = ch >> 4, c = ch & 15;
              int cs = (c & 8) | ((c ^ r) & 7);
              *(uint4*)&Ks[r * 128 + cs * 8] = kr[i]; }
            { int d = ch >> 3, c2 = ch & 7;
              int cs2 = (c2 ^ d) & 7;
              *(uint4*)&Vts[d * 64 + cs2 * 8] = vr[i]; }
        }
        __syncthreads();

        // ---- S = Q K^T, mask (only near diagonal), ^4, write P to LDS
        bf16x8 kf[2][4];
        #pragma unroll
        for (int ni = 0; ni < 2; ++ni)
            #pragma unroll
            for (int kk = 0; kk < 4; ++kk) {
                int row = wn * 32 + ni * 16 + lr;
                int c = kk * 4 + lg;
                int cs = (c & 8) | ((c ^ row) & 7);
                kf[ni][kk] = *(const bf16x8*)&Ks[row * 128 + cs * 8];
            }
        const bool nomask = (k0 + 63 <= q0 + wm * 64);
        #pragma unroll
        for (int mi = 0; mi < 4; ++mi) {
            f32x4 sa0 = f32x4{0.f, 0.f, 0.f, 0.f};
            f32x4 sa1 = f32x4{0.f, 0.f, 0.f, 0.f};
            #pragma unroll
            for (int kk = 0; kk < 4; ++kk) {
                sa0 = __builtin_amdgcn_mfma_f32_16x16x32_bf16(qf[mi][kk], kf[0][kk], sa0, 0, 0, 0);
                sa1 = __builtin_amdgcn_mfma_f32_16x16x32_bf16(qf[mi][kk], kf[1][kk], sa1, 0, 0, 0);
            }
            int gk0 = k0 + wn * 32 + lr;
            int gk1 = gk0 + 16;
            int c0w = wn * 4 + (lr >> 3);
            int c1w = c0w + 2;
            #pragma unroll
            for (int r = 0; r < 4; ++r) {
                int rowl = wm * 64 + mi * 16 + lg * 4 + r;
                float s0 = sa0[r], s1 = sa1[r];
                float t0 = s0 * s0, t1 = s1 * s1;
                float p0 = t0 * t0, p1 = t1 * t1;
                if (!nomask) {
                    int gq = q0 + rowl;
                    p0 = (gk0 <= gq) ? p0 : 0.0f;
                    p1 = (gk1 <= gq) ? p1 : 0.0f;
                }
                Ps[rowl * 64 + ((c0w ^ rowl) & 7) * 8 + (lr & 7)] = f2bf(p0);
                Ps[rowl * 64 + ((c1w ^ rowl) & 7) * 8 + (lr & 7)] = f2bf(p1);
            }
        }
        __syncthreads();   // P visible across wn-pairs

        // ---- O += P V,  denom += P * ones
        #pragma unroll
        for (int kk = 0; kk < 2; ++kk) {
            bf16x8 pf[4], vf[4];
            #pragma unroll
            for (int mi = 0; mi < 4; ++mi) {
                int row = wm * 64 + mi * 16 + lr;
                int cs = ((kk * 4 + lg) ^ row) & 7;
                pf[mi] = *(const bf16x8*)&Ps[row * 64 + cs * 8];
            }
            #pragma unroll
            for (int ni = 0; ni < 4; ++ni) {
                int row = wn * 64 + ni * 16 + lr;
                int cs = ((kk * 4 + lg) ^ row) & 7;
                vf[ni] = *(const bf16x8*)&Vts[row * 64 + cs * 8];
            }
            #pragma unroll
            for (int mi = 0; mi < 4; ++mi) {
                #pragma unroll
                for (int ni = 0; ni < 4; ++ni)
                    acc[mi][ni] = __builtin_amdgcn_mfma_f32_16x16x32_bf16(pf[mi], vf[ni], acc[mi][ni], 0, 0, 0);
                accd[mi] = __builtin_amdgcn_mfma_f32_16x16x32_bf16(pf[mi], onesf, accd[mi], 0, 0, 0);
            }
        }
    }

    // epilogue: out = acc / denom, staged via LDS for coalesced global writes
    __syncthreads();
    unsigned short* Cs = pool;   // [128][128]
    #pragma unroll
    for (int mi = 0; mi < 4; ++mi) {
        #pragma unroll
        for (int r = 0; r < 4; ++r) {
            float dv = __shfl(accd[mi][r], lane & 48);  // col 0 lives in lane lg*16
            float rinv = 1.0f / dv;
            int rowl = wm * 64 + mi * 16 + lg * 4 + r;
            #pragma unroll
            for (int ni = 0; ni < 4; ++ni)
                Cs[rowl * 128 + wn * 64 + ni * 16 + lr] = f2bf(acc[mi][ni][r] * rinv);
        }
    }
    __syncthreads();
    #pragma unroll
    for (int i = 0; i < 8; ++i) {
        int ch = i * 256 + t;
        int row = ch >> 4, c8 = (ch & 15) * 8;
        *(uint4*)&O[(size_t)(q0 + row) * EDIM + h * HD + c8] = *(const uint4*)&Cs[row * 128 + c8];
    }
}

// ---------------------------------------------------------------- launch
extern "C" void kernel_launch(void* const* d_in, const int* in_sizes, int n_in,
                              void* d_out, int out_size, void* d_ws, size_t ws_size,
                              hipStream_t stream) {
    const float* x        = (const float*)d_in[0];
    const float* w_qkv    = (const float*)d_in[1];
    const float* w_out    = (const float*)d_in[2];
    const float* ln_scale = (const float*)d_in[3];
    const float* ln_bias  = (const float*)d_in[4];

    if (ws_size < 134217728u) return;  // need 128 MiB

    char* ws = (char*)d_ws;
    unsigned short* xb    = (unsigned short*)(ws);              // 16 MiB; reused as attnO
    unsigned short* wqkvT = (unsigned short*)(ws + 16777216);   // 24 MiB; reused as Qh
    unsigned short* woutT = (unsigned short*)(ws + 41943040);   //  8 MiB
    unsigned short* proj  = (unsigned short*)(ws + 50331648);   // 48 MiB
    unsigned short* Kh    = (unsigned short*)(ws + 100663296);  // 16 MiB
    unsigned short* Vt    = (unsigned short*)(ws + 117440512);  // 16 MiB
    unsigned short* Qh    = wqkvT;   // alias: w_qkvT dead after GEMM1
    unsigned short* attnO = xb;      // alias: xb dead after GEMM1

    k_convert_x<<<2048, 256, 0, stream>>>(x, xb, (N_SEQ * EDIM) / 4);
    k_transpose_f32_bf16<<<dim3(3 * EDIM / 64, EDIM / 64), 256, 0, stream>>>(w_qkv, wqkvT, EDIM, 3 * EDIM);
    k_transpose_f32_bf16<<<dim3(EDIM / 64, EDIM / 64), 256, 0, stream>>>(w_out, woutT, EDIM, EDIM);
    k_gemm_bt<0><<<dim3(3 * EDIM / 128, N_SEQ / 128), 256, 0, stream>>>(xb, wqkvT, proj, N_SEQ, 3 * EDIM, EDIM);
    k_ropeln<<<N_SEQ, 256, 0, stream>>>(proj, ln_scale, ln_bias, Qh, Kh);
    k_vtrans<<<dim3(N_SEQ / 64, NH), 256, 0, stream>>>(proj, Vt);
    k_attn<<<512, 256, 0, stream>>>(Qh, Kh, Vt, attnO);
    k_gemm_bt<1><<<dim3(EDIM / 128, N_SEQ / 128), 256, 0, stream>>>(attnO, woutT, (float*)d_out, N_SEQ, EDIM, EDIM);
}

// Round 6
// 324.993 us; speedup vs baseline: 1.6938x; 1.6938x over previous
//
#include <hip/hip_runtime.h>
#include <stdint.h>
#include <math.h>

// Problem constants
#define N_SEQ 4096
#define EDIM  2048
#define NH    16
#define HD    128

typedef __attribute__((ext_vector_type(8))) short bf16x8;
typedef __attribute__((ext_vector_type(4))) float f32x4;

#define AS1 __attribute__((address_space(1)))
#define AS3 __attribute__((address_space(3)))

__device__ __forceinline__ void gll16(const unsigned short* g, unsigned short* l) {
    __builtin_amdgcn_global_load_lds((const AS1 unsigned int*)g,
                                     (AS3 unsigned int*)l, 16, 0, 0);
}

__device__ __forceinline__ unsigned short f2bf(float f) {
    union { float f; unsigned u; } v; v.f = f;
    unsigned r = v.u + 0x7FFFu + ((v.u >> 16) & 1u);
    return (unsigned short)(r >> 16);
}
__device__ __forceinline__ float bf2f(unsigned short h) {
    union { unsigned u; float f; } v; v.u = ((unsigned)h) << 16;
    return v.f;
}

// ---------------------------------------------------------------- convert x
__global__ void k_convert_x(const float* __restrict__ x,
                            unsigned short* __restrict__ xb, int n4) {
    int i = blockIdx.x * blockDim.x + threadIdx.x;
    int stride = gridDim.x * blockDim.x;
    for (; i < n4; i += stride) {
        float4 v = ((const float4*)x)[i];
        ushort4 o;
        o.x = f2bf(v.x); o.y = f2bf(v.y); o.z = f2bf(v.z); o.w = f2bf(v.w);
        ((ushort4*)xb)[i] = o;
    }
}

// ---------------------------------------------- transpose f32 (RxC) -> bf16 (CxR)
__global__ void k_transpose_f32_bf16(const float* __restrict__ in,
                                     unsigned short* __restrict__ out,
                                     int R, int C) {
    __shared__ unsigned short Ls[64][68];
    const int c0 = blockIdx.x * 64, r0 = blockIdx.y * 64;
    const int t = threadIdx.x;
    #pragma unroll
    for (int i = 0; i < 4; ++i) {
        int ch = i * 256 + t;              // 1024 float4 chunks
        int r = ch >> 4, c4 = (ch & 15) * 4;
        float4 v = *(const float4*)&in[(size_t)(r0 + r) * C + c0 + c4];
        ushort4 o;
        o.x = f2bf(v.x); o.y = f2bf(v.y); o.z = f2bf(v.z); o.w = f2bf(v.w);
        *(ushort4*)&Ls[r][c4] = o;
    }
    __syncthreads();
    #pragma unroll
    for (int i = 0; i < 2; ++i) {
        int ch = i * 256 + t;              // 512 chunks of 8 bf16
        int rr = ch >> 3, c8 = (ch & 7) * 8;
        unsigned short vals[8];
        #pragma unroll
        for (int j = 0; j < 8; ++j) vals[j] = Ls[c8 + j][rr];
        uint4 pk;
        pk.x = (unsigned)vals[0] | ((unsigned)vals[1] << 16);
        pk.y = (unsigned)vals[2] | ((unsigned)vals[3] << 16);
        pk.z = (unsigned)vals[4] | ((unsigned)vals[5] << 16);
        pk.w = (unsigned)vals[6] | ((unsigned)vals[7] << 16);
        *(uint4*)&out[(size_t)(c0 + rr) * R + r0 + c8] = pk;
    }
}

// ---------------------------------------------------------------- bt GEMM
// C[M,N] = A[M,K] * Bt[N,K]^T  (bf16 in, f32 acc, bf16 or f32 out)
template<int F32OUT>
__launch_bounds__(256, 2)
__global__ void k_gemm_bt(const unsigned short* __restrict__ A,
                          const unsigned short* __restrict__ Bt,
                          void* __restrict__ C,
                          int M, int N, int K) {
    __shared__ unsigned short sh[2 * 128 * 64];   // As | Bs, linear [128][64]
    unsigned short* As = sh;
    unsigned short* Bs = sh + 128 * 64;

    const int t = threadIdx.x;
    const int wave = t >> 6, lane = t & 63;
    const int wm = wave >> 1, wn = wave & 1;
    const int lg = lane >> 4, lr = lane & 15;

    // XCD-aware bijective swizzle (nwg % 8 == 0 for all our grids)
    const int nbx = gridDim.x;
    const int nwg = nbx * gridDim.y;
    int bid = blockIdx.y * nbx + blockIdx.x;
    int swz = (bid & 7) * (nwg >> 3) + (bid >> 3);
    const int m0 = (swz / nbx) * 128;
    const int n0 = (swz % nbx) * 128;

    const unsigned short* aptr = A  + (size_t)m0 * K;
    const unsigned short* bptr = Bt + (size_t)n0 * K;

    f32x4 acc[4][4];
    #pragma unroll
    for (int i = 0; i < 4; ++i)
        #pragma unroll
        for (int j = 0; j < 4; ++j) acc[i][j] = f32x4{0.f, 0.f, 0.f, 0.f};

    // per-thread staging geometry (loop-invariant)
    int schr[4], srow[4], scb[4];
    #pragma unroll
    for (int i = 0; i < 4; ++i) {
        int ch = (i * 4 + wave) * 64 + lane;   // 0..1023, wave-uniform base + lane
        schr[i] = ch;
        srow[i] = ch >> 3;
        scb[i]  = (ch & 7) ^ ((ch >> 3) & 7);  // inverse-swizzled source col-block
    }

    const int nkb = K >> 6;
    for (int kb = 0; kb < nkb; ++kb) {
        __syncthreads();   // previous iter's ds_reads done before overwrite
        #pragma unroll
        for (int i = 0; i < 4; ++i) {
            const size_t goff = (size_t)srow[i] * K + (size_t)kb * 64 + scb[i] * 8;
            gll16(&aptr[goff], &As[schr[i] * 8]);
            gll16(&bptr[goff], &Bs[schr[i] * 8]);
        }
        __syncthreads();   // drains vmcnt+lgkm (compiler-inserted before barrier)

        #pragma unroll
        for (int kk = 0; kk < 2; ++kk) {
            bf16x8 af[4], bf[4];
            const int cbx = ((kk * 4 + lg) ^ (lr & 7)) * 8;  // swizzled read col
            #pragma unroll
            for (int i = 0; i < 4; ++i) {
                af[i] = *(const bf16x8*)&As[(wm * 64 + i * 16 + lr) * 64 + cbx];
                bf[i] = *(const bf16x8*)&Bs[(wn * 64 + i * 16 + lr) * 64 + cbx];
            }
            #pragma unroll
            for (int i = 0; i < 4; ++i)
                #pragma unroll
                for (int j = 0; j < 4; ++j)
                    acc[i][j] = __builtin_amdgcn_mfma_f32_16x16x32_bf16(af[i], bf[j], acc[i][j], 0, 0, 0);
        }
    }

    if (F32OUT) {
        #pragma unroll
        for (int i = 0; i < 4; ++i) {
            int row0 = m0 + wm * 64 + i * 16 + lg * 4;
            #pragma unroll
            for (int j = 0; j < 4; ++j) {
                int col = n0 + wn * 64 + j * 16 + lr;
                #pragma unroll
                for (int r = 0; r < 4; ++r)
                    ((float*)C)[(size_t)(row0 + r) * N + col] = acc[i][j][r];
            }
        }
    } else {
        // stage bf16 C-tile in LDS, write out coalesced uint4 rows
        __syncthreads();
        unsigned short* Cs = sh;     // [128][128]
        #pragma unroll
        for (int i = 0; i < 4; ++i) {
            #pragma unroll
            for (int j = 0; j < 4; ++j) {
                int col = wn * 64 + j * 16 + lr;
                #pragma unroll
                for (int r = 0; r < 4; ++r)
                    Cs[(wm * 64 + i * 16 + lg * 4 + r) * 128 + col] = f2bf(acc[i][j][r]);
            }
        }
        __syncthreads();
        #pragma unroll
        for (int i = 0; i < 8; ++i) {
            int ch = i * 256 + t;             // 2048 chunks of 8 shorts
            int row = ch >> 4, c8 = (ch & 15) * 8;
            *(uint4*)&((unsigned short*)C)[(size_t)(m0 + row) * N + n0 + c8] =
                *(const uint4*)&Cs[row * 128 + c8];
        }
    }
}

// ------------------------------------------------------- RoPE + LayerNorm (q,k)
__global__ void k_ropeln(const unsigned short* __restrict__ proj,
                         const float* __restrict__ ln_scale,
                         const float* __restrict__ ln_bias,
                         unsigned short* __restrict__ Qh,
                         unsigned short* __restrict__ Kh) {
    const int n = blockIdx.x;
    const int wave = threadIdx.x >> 6, lane = threadIdx.x & 63;
    float inv = expf(-((float)(2 * lane) / 128.0f) * 9.210340371976184f);
    float ang = (float)n * inv;
    float c = cosf(ang), s = sinf(ang);
    const float sc1 = ln_scale[lane], sc2 = ln_scale[lane + 64];
    const float b1 = ln_bias[lane],  b2 = ln_bias[lane + 64];

    for (int r = wave; r < 32; r += 4) {
        int h = r >> 1, qk = r & 1;
        const unsigned short* src = proj + (size_t)n * (3 * EDIM) + qk * EDIM + h * HD;
        float x1 = bf2f(src[lane]), x2 = bf2f(src[lane + 64]);
        float o1 = x1 * c - x2 * s;
        float o2 = x1 * s + x2 * c;
        float sum = o1 + o2, sq = o1 * o1 + o2 * o2;
        #pragma unroll
        for (int d = 1; d < 64; d <<= 1) {
            sum += __shfl_xor(sum, d);
            sq  += __shfl_xor(sq, d);
        }
        float mean = sum * (1.0f / 128.0f);
        float var = sq * (1.0f / 128.0f) - mean * mean;
        float rstd = rsqrtf(var + 1e-5f);
        float y1 = (o1 - mean) * rstd * sc1 + b1;
        float y2 = (o2 - mean) * rstd * sc2 + b2;
        unsigned short* dst = (qk ? Kh : Qh) + ((size_t)h * N_SEQ + n) * HD;
        dst[lane]      = f2bf(y1);
        dst[lane + 64] = f2bf(y2);
    }
}

// ---------------------------------------------------- V transpose: [n][d] -> [d][n]
__global__ void k_vtrans(const unsigned short* __restrict__ proj,
                         unsigned short* __restrict__ Vt) {
    __shared__ unsigned short Ls[64][136];
    const int h = blockIdx.y;
    const int n0 = blockIdx.x * 64;
    const int t = threadIdx.x;
    #pragma unroll
    for (int i = 0; i < 4; ++i) {
        int ch = i * 256 + t;
        int r = ch >> 4, d0 = (ch & 15) * 8;
        uint4 v = *(const uint4*)&proj[(size_t)(n0 + r) * (3 * EDIM) + 2 * EDIM + h * HD + d0];
        *(uint4*)&Ls[r][d0] = v;
    }
    __syncthreads();
    #pragma unroll
    for (int i = 0; i < 4; ++i) {
        int ch = i * 256 + t;
        int d = ch >> 3, nb = (ch & 7) * 8;
        unsigned short vals[8];
        #pragma unroll
        for (int j = 0; j < 8; ++j) vals[j] = Ls[nb + j][d];
        uint4 pk;
        pk.x = (unsigned)vals[0] | ((unsigned)vals[1] << 16);
        pk.y = (unsigned)vals[2] | ((unsigned)vals[3] << 16);
        pk.z = (unsigned)vals[4] | ((unsigned)vals[5] << 16);
        pk.w = (unsigned)vals[6] | ((unsigned)vals[7] << 16);
        *(uint4*)&Vt[((size_t)h * HD + d) * N_SEQ + n0 + nb] = pk;
    }
}

// ------------------------------------------------------- polynomial attention
// Qh,Kh: [NH][N_SEQ][HD], Vt: [NH][HD][N_SEQ]. O: [N_SEQ][EDIM] bf16.
// v5: global_load_lds staging (zero staging VGPRs), double-buffered K/V with
// counted vmcnt(8) + raw barriers (2/iter), wave-private P, head-per-XCD
// mapping, heavy+light block pairing per CU.
// Per tile: K = 64x128 = 1024 chunks (4/thr), V = 128x64 = 1024 chunks (4/thr).
__launch_bounds__(256, 2)
__global__ void k_attn(const unsigned short* __restrict__ Qh,
                       const unsigned short* __restrict__ Kh,
                       const unsigned short* __restrict__ Vt,
                       unsigned short* __restrict__ O) {
    // pool: Ks[2][64][128] | Vts[2][128][64] | Ps[4][32][64]  = 80 KB
    __shared__ unsigned short pool[5 * 8192];

    const int t = threadIdx.x;
    const int w = t >> 6, lane = t & 63;
    const int lg = lane >> 4, lr = lane & 15;

    // block decode: s%8 = XCD = h>>1 (2 heads per XCD); batch pairing balances
    // per-CU work at 66 iters (heavy 31-qq first, light qq second).
    const int s = blockIdx.x & 255;
    const int batch = blockIdx.x >> 8;
    const int x = s & 7;
    const int hb = (s >> 3) & 1;
    const int h = x * 2 + hb;
    const int qq = s >> 4;
    const int qb = batch ? qq : (31 - qq);
    const int q0 = qb * 128;
    const int qbase = q0 + w * 32;   // this wave's first q-row

    // Q fragments in registers (wave's 32 queries x 128 d)
    bf16x8 qf[2][4];
    #pragma unroll
    for (int mi = 0; mi < 2; ++mi)
        #pragma unroll
        for (int kk = 0; kk < 4; ++kk)
            qf[mi][kk] = *(const bf16x8*)&Qh[((size_t)h * N_SEQ + qbase + mi * 16 + lr) * HD + kk * 32 + lg * 8];

    f32x4 acc[2][8];
    #pragma unroll
    for (int i = 0; i < 2; ++i)
        #pragma unroll
        for (int j = 0; j < 8; ++j) acc[i][j] = f32x4{0.f, 0.f, 0.f, 0.f};
    f32x4 accd[2];
    accd[0] = f32x4{0.f, 0.f, 0.f, 0.f};
    accd[1] = f32x4{0.f, 0.f, 0.f, 0.f};

    // ones B-fragment: row-sum lands in output col 0
    bf16x8 onesf;
    {
        short ov = (lr == 0) ? (short)0x3F80 : (short)0;
        #pragma unroll
        for (int j = 0; j < 8; ++j) onesf[j] = ov;
    }

    // staging geometry: K 1024 chunks (4/thread), V 1024 chunks (4/thread).
    // LDS linear dest (wave-uniform base + lane*16B); swizzle pre-applied to
    // the global source chunk index (involution), ds_read applies same XOR.
    int kch[4], vch[4];
    const unsigned short* kg[4];
    const unsigned short* vg[4];
    #pragma unroll
    for (int i = 0; i < 4; ++i) {
        int ch = i * 256 + t;
        kch[i] = ch;
        int r = ch >> 4, p = ch & 15;
        int csrc = (p & 8) | ((p ^ r) & 7);
        kg[i] = Kh + ((size_t)h * N_SEQ + r) * HD + csrc * 8;
    }
    #pragma unroll
    for (int i = 0; i < 4; ++i) {
        int ch = i * 256 + t;
        vch[i] = ch;
        int d = ch >> 3, p2 = ch & 7;       // d in [0,128), col chunk in [0,8)
        int c2src = (p2 ^ d) & 7;
        vg[i] = Vt + ((size_t)h * HD + d) * N_SEQ + c2src * 8;
    }

    const int nkb = 2 * qb + 2;

    // prologue: stage tile 0 into buf 0 (8 loads/thread)
    {
        #pragma unroll
        for (int i = 0; i < 4; ++i) { gll16(kg[i], pool + kch[i] * 8); kg[i] += 64 * HD; }
        #pragma unroll
        for (int i = 0; i < 4; ++i) { gll16(vg[i], pool + 16384 + vch[i] * 8); vg[i] += 64; }
    }

    unsigned short* Pw = pool + 32768 + w * 2048;   // wave-private [32][64]

    for (int kb = 0; kb < nkb; ++kb) {
        const int cur = kb & 1;
        const int k0 = kb * 64;

        if (kb + 1 < nkb) {
            const int nxt = cur ^ 1;
            unsigned short* Kn = pool + nxt * 8192;
            unsigned short* Vn = pool + 16384 + nxt * 8192;
            #pragma unroll
            for (int i = 0; i < 4; ++i) { gll16(kg[i], Kn + kch[i] * 8); kg[i] += 64 * HD; }
            #pragma unroll
            for (int i = 0; i < 4; ++i) { gll16(vg[i], Vn + vch[i] * 8); vg[i] += 64; }
            asm volatile("s_waitcnt vmcnt(8)" ::: "memory");   // tile kb's 8 landed
        } else {
            asm volatile("s_waitcnt vmcnt(0)" ::: "memory");
        }
        __builtin_amdgcn_s_barrier();   // buf[cur] ready for all waves

        const unsigned short* Kc = pool + cur * 8192;
        const unsigned short* Vc = pool + 16384 + cur * 8192;

        // ---- S = Q K^T  (wave-private: 32 q-rows x 64 keys)
        f32x4 sa[2][4];
        #pragma unroll
        for (int i = 0; i < 2; ++i)
            #pragma unroll
            for (int j = 0; j < 4; ++j) sa[i][j] = f32x4{0.f, 0.f, 0.f, 0.f};
        #pragma unroll
        for (int nn = 0; nn < 2; ++nn) {
            bf16x8 kf[2][4];
            #pragma unroll
            for (int nj = 0; nj < 2; ++nj)
                #pragma unroll
                for (int kk = 0; kk < 4; ++kk) {
                    int row = (nn * 2 + nj) * 16 + lr;
                    int c = kk * 4 + lg;
                    int cs = (c & 8) | ((c ^ row) & 7);
                    kf[nj][kk] = *(const bf16x8*)&Kc[row * 128 + cs * 8];
                }
            #pragma unroll
            for (int kk = 0; kk < 4; ++kk)
                #pragma unroll
                for (int nj = 0; nj < 2; ++nj)
                    #pragma unroll
                    for (int mi = 0; mi < 2; ++mi)
                        sa[mi][nn * 2 + nj] = __builtin_amdgcn_mfma_f32_16x16x32_bf16(
                            qf[mi][kk], kf[nj][kk], sa[mi][nn * 2 + nj], 0, 0, 0);
        }

        // ---- mask (only near diagonal), ^4, write P to wave-private LDS
        const bool nomask = (k0 + 63 <= qbase);
        #pragma unroll
        for (int mi = 0; mi < 2; ++mi)
            #pragma unroll
            for (int ni = 0; ni < 4; ++ni) {
                int gk = k0 + ni * 16 + lr;
                #pragma unroll
                for (int r = 0; r < 4; ++r) {
                    int rw = mi * 16 + lg * 4 + r;
                    float sv = sa[mi][ni][r];
                    float t2 = sv * sv;
                    float p = t2 * t2;
                    if (!nomask) p = (gk <= qbase + rw) ? p : 0.0f;
                    int ci = ni * 2 + (lr >> 3);
                    int cs = (ci ^ (rw & 7)) & 7;
                    Pw[rw * 64 + cs * 8 + (lr & 7)] = f2bf(p);
                }
            }

        // ---- O += P V, denom += P * ones   (same-wave P: lgkm dep only)
        #pragma unroll
        for (int kk = 0; kk < 2; ++kk) {
            bf16x8 pf[2];
            #pragma unroll
            for (int mi = 0; mi < 2; ++mi) {
                int row = mi * 16 + lr;
                int cs = ((kk * 4 + lg) ^ (row & 7)) & 7;
                pf[mi] = *(const bf16x8*)&Pw[row * 64 + cs * 8];
            }
            #pragma unroll
            for (int ni = 0; ni < 8; ++ni) {
                int row = ni * 16 + lr;
                int cs2 = ((kk * 4 + lg) ^ (row & 7)) & 7;
                bf16x8 vf = *(const bf16x8*)&Vc[row * 64 + cs2 * 8];
                #pragma unroll
                for (int mi = 0; mi < 2; ++mi)
                    acc[mi][ni] = __builtin_amdgcn_mfma_f32_16x16x32_bf16(pf[mi], vf, acc[mi][ni], 0, 0, 0);
            }
            #pragma unroll
            for (int mi = 0; mi < 2; ++mi)
                accd[mi] = __builtin_amdgcn_mfma_f32_16x16x32_bf16(pf[mi], onesf, accd[mi], 0, 0, 0);
        }

        __builtin_amdgcn_s_barrier();   // all waves done reading buf[cur]
    }

    // epilogue: out = acc / denom, staged via LDS (overlays Ks bufs)
    unsigned short* Cs = pool;   // [128][128] = 32 KB
    #pragma unroll
    for (int mi = 0; mi < 2; ++mi) {
        #pragma unroll
        for (int r = 0; r < 4; ++r) {
            float dv = __shfl(accd[mi][r], lane & 48);  // col 0 lives in lane lg*16
            float rinv = 1.0f / dv;
            int rw = w * 32 + mi * 16 + lg * 4 + r;
            #pragma unroll
            for (int ni = 0; ni < 8; ++ni)
                Cs[rw * 128 + ni * 16 + lr] = f2bf(acc[mi][ni][r] * rinv);
        }
    }
    __syncthreads();
    #pragma unroll
    for (int i = 0; i < 8; ++i) {
        int ch = i * 256 + t;
        int row = ch >> 4, c8 = (ch & 15) * 8;
        *(uint4*)&O[(size_t)(q0 + row) * EDIM + h * HD + c8] = *(const uint4*)&Cs[row * 128 + c8];
    }
}

// ---------------------------------------------------------------- launch
extern "C" void kernel_launch(void* const* d_in, const int* in_sizes, int n_in,
                              void* d_out, int out_size, void* d_ws, size_t ws_size,
                              hipStream_t stream) {
    const float* x        = (const float*)d_in[0];
    const float* w_qkv    = (const float*)d_in[1];
    const float* w_out    = (const float*)d_in[2];
    const float* ln_scale = (const float*)d_in[3];
    const float* ln_bias  = (const float*)d_in[4];

    if (ws_size < 134217728u) return;  // need 128 MiB

    char* ws = (char*)d_ws;
    unsigned short* xb    = (unsigned short*)(ws);              // 16 MiB; reused as attnO
    unsigned short* wqkvT = (unsigned short*)(ws + 16777216);   // 24 MiB; reused as Qh
    unsigned short* woutT = (unsigned short*)(ws + 41943040);   //  8 MiB
    unsigned short* proj  = (unsigned short*)(ws + 50331648);   // 48 MiB
    unsigned short* Kh    = (unsigned short*)(ws + 100663296);  // 16 MiB
    unsigned short* Vt    = (unsigned short*)(ws + 117440512);  // 16 MiB
    unsigned short* Qh    = wqkvT;   // alias: w_qkvT dead after GEMM1
    unsigned short* attnO = xb;      // alias: xb dead after GEMM1

    k_convert_x<<<2048, 256, 0, stream>>>(x, xb, (N_SEQ * EDIM) / 4);
    k_transpose_f32_bf16<<<dim3(3 * EDIM / 64, EDIM / 64), 256, 0, stream>>>(w_qkv, wqkvT, EDIM, 3 * EDIM);
    k_transpose_f32_bf16<<<dim3(EDIM / 64, EDIM / 64), 256, 0, stream>>>(w_out, woutT, EDIM, EDIM);
    k_gemm_bt<0><<<dim3(3 * EDIM / 128, N_SEQ / 128), 256, 0, stream>>>(xb, wqkvT, proj, N_SEQ, 3 * EDIM, EDIM);
    k_ropeln<<<N_SEQ, 256, 0, stream>>>(proj, ln_scale, ln_bias, Qh, Kh);
    k_vtrans<<<dim3(N_SEQ / 64, NH), 256, 0, stream>>>(proj, Vt);
    k_attn<<<512, 256, 0, stream>>>(Qh, Kh, Vt, attnO);
    k_gemm_bt<1><<<dim3(EDIM / 128, N_SEQ / 128), 256, 0, stream>>>(attnO, woutT, (float*)d_out, N_SEQ, EDIM, EDIM);
}

// Round 7
// 312.818 us; speedup vs baseline: 1.7598x; 1.0389x over previous
//
#include <hip/hip_runtime.h>
#include <stdint.h>
#include <math.h>

// Problem constants
#define N_SEQ 4096
#define EDIM  2048
#define NH    16
#define HD    128

typedef __attribute__((ext_vector_type(8))) short bf16x8;
typedef __attribute__((ext_vector_type(4))) float f32x4;

#define AS1 __attribute__((address_space(1)))
#define AS3 __attribute__((address_space(3)))

__device__ __forceinline__ void gll16(const unsigned short* g, unsigned short* l) {
    __builtin_amdgcn_global_load_lds((const AS1 unsigned int*)g,
                                     (AS3 unsigned int*)l, 16, 0, 0);
}

__device__ __forceinline__ unsigned short f2bf(float f) {
    union { float f; unsigned u; } v; v.f = f;
    unsigned r = v.u + 0x7FFFu + ((v.u >> 16) & 1u);
    return (unsigned short)(r >> 16);
}
__device__ __forceinline__ float bf2f(unsigned short h) {
    union { unsigned u; float f; } v; v.u = ((unsigned)h) << 16;
    return v.f;
}

// ---------------------------------------------------------------- convert x
__global__ void k_convert_x(const float* __restrict__ x,
                            unsigned short* __restrict__ xb, int n4) {
    int i = blockIdx.x * blockDim.x + threadIdx.x;
    int stride = gridDim.x * blockDim.x;
    for (; i < n4; i += stride) {
        float4 v = ((const float4*)x)[i];
        ushort4 o;
        o.x = f2bf(v.x); o.y = f2bf(v.y); o.z = f2bf(v.z); o.w = f2bf(v.w);
        ((ushort4*)xb)[i] = o;
    }
}

// ---------------------------------------------- transpose f32 (RxC) -> bf16 (CxR)
__global__ void k_transpose_f32_bf16(const float* __restrict__ in,
                                     unsigned short* __restrict__ out,
                                     int R, int C) {
    __shared__ unsigned short Ls[64][68];
    const int c0 = blockIdx.x * 64, r0 = blockIdx.y * 64;
    const int t = threadIdx.x;
    #pragma unroll
    for (int i = 0; i < 4; ++i) {
        int ch = i * 256 + t;              // 1024 float4 chunks
        int r = ch >> 4, c4 = (ch & 15) * 4;
        float4 v = *(const float4*)&in[(size_t)(r0 + r) * C + c0 + c4];
        ushort4 o;
        o.x = f2bf(v.x); o.y = f2bf(v.y); o.z = f2bf(v.z); o.w = f2bf(v.w);
        *(ushort4*)&Ls[r][c4] = o;
    }
    __syncthreads();
    #pragma unroll
    for (int i = 0; i < 2; ++i) {
        int ch = i * 256 + t;              // 512 chunks of 8 bf16
        int rr = ch >> 3, c8 = (ch & 7) * 8;
        unsigned short vals[8];
        #pragma unroll
        for (int j = 0; j < 8; ++j) vals[j] = Ls[c8 + j][rr];
        uint4 pk;
        pk.x = (unsigned)vals[0] | ((unsigned)vals[1] << 16);
        pk.y = (unsigned)vals[2] | ((unsigned)vals[3] << 16);
        pk.z = (unsigned)vals[4] | ((unsigned)vals[5] << 16);
        pk.w = (unsigned)vals[6] | ((unsigned)vals[7] << 16);
        *(uint4*)&out[(size_t)(c0 + rr) * R + r0 + c8] = pk;
    }
}

// ---------------------------------------------------------------- bt GEMM
// C[M,N] = A[M,K] * Bt[N,K]^T  (bf16 in, f32 acc, bf16 or f32 out)
template<int F32OUT>
__launch_bounds__(256, 2)
__global__ void k_gemm_bt(const unsigned short* __restrict__ A,
                          const unsigned short* __restrict__ Bt,
                          void* __restrict__ C,
                          int M, int N, int K) {
    __shared__ unsigned short sh[2 * 128 * 64];   // As | Bs, linear [128][64]
    unsigned short* As = sh;
    unsigned short* Bs = sh + 128 * 64;

    const int t = threadIdx.x;
    const int wave = t >> 6, lane = t & 63;
    const int wm = wave >> 1, wn = wave & 1;
    const int lg = lane >> 4, lr = lane & 15;

    // XCD-aware bijective swizzle (nwg % 8 == 0 for all our grids)
    const int nbx = gridDim.x;
    const int nwg = nbx * gridDim.y;
    int bid = blockIdx.y * nbx + blockIdx.x;
    int swz = (bid & 7) * (nwg >> 3) + (bid >> 3);
    const int m0 = (swz / nbx) * 128;
    const int n0 = (swz % nbx) * 128;

    const unsigned short* aptr = A  + (size_t)m0 * K;
    const unsigned short* bptr = Bt + (size_t)n0 * K;

    f32x4 acc[4][4];
    #pragma unroll
    for (int i = 0; i < 4; ++i)
        #pragma unroll
        for (int j = 0; j < 4; ++j) acc[i][j] = f32x4{0.f, 0.f, 0.f, 0.f};

    // per-thread staging geometry (loop-invariant)
    int schr[4], srow[4], scb[4];
    #pragma unroll
    for (int i = 0; i < 4; ++i) {
        int ch = (i * 4 + wave) * 64 + lane;   // 0..1023, wave-uniform base + lane
        schr[i] = ch;
        srow[i] = ch >> 3;
        scb[i]  = (ch & 7) ^ ((ch >> 3) & 7);  // inverse-swizzled source col-block
    }

    const int nkb = K >> 6;
    for (int kb = 0; kb < nkb; ++kb) {
        __syncthreads();   // previous iter's ds_reads done before overwrite
        #pragma unroll
        for (int i = 0; i < 4; ++i) {
            const size_t goff = (size_t)srow[i] * K + (size_t)kb * 64 + scb[i] * 8;
            gll16(&aptr[goff], &As[schr[i] * 8]);
            gll16(&bptr[goff], &Bs[schr[i] * 8]);
        }
        __syncthreads();   // drains vmcnt+lgkm (compiler-inserted before barrier)

        #pragma unroll
        for (int kk = 0; kk < 2; ++kk) {
            bf16x8 af[4], bf[4];
            const int cbx = ((kk * 4 + lg) ^ (lr & 7)) * 8;  // swizzled read col
            #pragma unroll
            for (int i = 0; i < 4; ++i) {
                af[i] = *(const bf16x8*)&As[(wm * 64 + i * 16 + lr) * 64 + cbx];
                bf[i] = *(const bf16x8*)&Bs[(wn * 64 + i * 16 + lr) * 64 + cbx];
            }
            #pragma unroll
            for (int i = 0; i < 4; ++i)
                #pragma unroll
                for (int j = 0; j < 4; ++j)
                    acc[i][j] = __builtin_amdgcn_mfma_f32_16x16x32_bf16(af[i], bf[j], acc[i][j], 0, 0, 0);
        }
    }

    if (F32OUT) {
        #pragma unroll
        for (int i = 0; i < 4; ++i) {
            int row0 = m0 + wm * 64 + i * 16 + lg * 4;
            #pragma unroll
            for (int j = 0; j < 4; ++j) {
                int col = n0 + wn * 64 + j * 16 + lr;
                #pragma unroll
                for (int r = 0; r < 4; ++r)
                    ((float*)C)[(size_t)(row0 + r) * N + col] = acc[i][j][r];
            }
        }
    } else {
        // stage bf16 C-tile in LDS, write out coalesced uint4 rows
        __syncthreads();
        unsigned short* Cs = sh;     // [128][128]
        #pragma unroll
        for (int i = 0; i < 4; ++i) {
            #pragma unroll
            for (int j = 0; j < 4; ++j) {
                int col = wn * 64 + j * 16 + lr;
                #pragma unroll
                for (int r = 0; r < 4; ++r)
                    Cs[(wm * 64 + i * 16 + lg * 4 + r) * 128 + col] = f2bf(acc[i][j][r]);
            }
        }
        __syncthreads();
        #pragma unroll
        for (int i = 0; i < 8; ++i) {
            int ch = i * 256 + t;             // 2048 chunks of 8 shorts
            int row = ch >> 4, c8 = (ch & 15) * 8;
            *(uint4*)&((unsigned short*)C)[(size_t)(m0 + row) * N + n0 + c8] =
                *(const uint4*)&Cs[row * 128 + c8];
        }
    }
}

// ------------------------------------------------------- RoPE + LayerNorm (q,k)
__global__ void k_ropeln(const unsigned short* __restrict__ proj,
                         const float* __restrict__ ln_scale,
                         const float* __restrict__ ln_bias,
                         unsigned short* __restrict__ Qh,
                         unsigned short* __restrict__ Kh) {
    const int n = blockIdx.x;
    const int wave = threadIdx.x >> 6, lane = threadIdx.x & 63;
    float inv = expf(-((float)(2 * lane) / 128.0f) * 9.210340371976184f);
    float ang = (float)n * inv;
    float c = cosf(ang), s = sinf(ang);
    const float sc1 = ln_scale[lane], sc2 = ln_scale[lane + 64];
    const float b1 = ln_bias[lane],  b2 = ln_bias[lane + 64];

    for (int r = wave; r < 32; r += 4) {
        int h = r >> 1, qk = r & 1;
        const unsigned short* src = proj + (size_t)n * (3 * EDIM) + qk * EDIM + h * HD;
        float x1 = bf2f(src[lane]), x2 = bf2f(src[lane + 64]);
        float o1 = x1 * c - x2 * s;
        float o2 = x1 * s + x2 * c;
        float sum = o1 + o2, sq = o1 * o1 + o2 * o2;
        #pragma unroll
        for (int d = 1; d < 64; d <<= 1) {
            sum += __shfl_xor(sum, d);
            sq  += __shfl_xor(sq, d);
        }
        float mean = sum * (1.0f / 128.0f);
        float var = sq * (1.0f / 128.0f) - mean * mean;
        float rstd = rsqrtf(var + 1e-5f);
        float y1 = (o1 - mean) * rstd * sc1 + b1;
        float y2 = (o2 - mean) * rstd * sc2 + b2;
        unsigned short* dst = (qk ? Kh : Qh) + ((size_t)h * N_SEQ + n) * HD;
        dst[lane]      = f2bf(y1);
        dst[lane + 64] = f2bf(y2);
    }
}

// ---------------------------------------------------- V transpose: [n][d] -> [d][n]
__global__ void k_vtrans(const unsigned short* __restrict__ proj,
                         unsigned short* __restrict__ Vt) {
    __shared__ unsigned short Ls[64][136];
    const int h = blockIdx.y;
    const int n0 = blockIdx.x * 64;
    const int t = threadIdx.x;
    #pragma unroll
    for (int i = 0; i < 4; ++i) {
        int ch = i * 256 + t;
        int r = ch >> 4, d0 = (ch & 15) * 8;
        uint4 v = *(const uint4*)&proj[(size_t)(n0 + r) * (3 * EDIM) + 2 * EDIM + h * HD + d0];
        *(uint4*)&Ls[r][d0] = v;
    }
    __syncthreads();
    #pragma unroll
    for (int i = 0; i < 4; ++i) {
        int ch = i * 256 + t;
        int d = ch >> 3, nb = (ch & 7) * 8;
        unsigned short vals[8];
        #pragma unroll
        for (int j = 0; j < 8; ++j) vals[j] = Ls[nb + j][d];
        uint4 pk;
        pk.x = (unsigned)vals[0] | ((unsigned)vals[1] << 16);
        pk.y = (unsigned)vals[2] | ((unsigned)vals[3] << 16);
        pk.z = (unsigned)vals[4] | ((unsigned)vals[5] << 16);
        pk.w = (unsigned)vals[6] | ((unsigned)vals[7] << 16);
        *(uint4*)&Vt[((size_t)h * HD + d) * N_SEQ + n0 + nb] = pk;
    }
}

// ------------------------------------------------------- polynomial attention
// Qh,Kh: [NH][N_SEQ][HD], Vt: [NH][HD][N_SEQ]. O: [N_SEQ][EDIM] bf16.
// v6: swapped QK^T (mfma(K,Q) -> S^T) so P stays in REGISTERS: the 32 masked
// s^4 values pack via v_cvt_pk_bf16_f32 straight into PV A-fragments under a
// virtual K-permutation sigma(lane,slot) that V's reads replicate (2x b64 at
// sigma offsets). Removes the P LDS round-trip (32 ds_write_b16 + lgkm +
// 4 ds_read_b128) + ~120 VALU/iter. T5 setprio around MFMA clusters.
// Staging: global_load_lds, double-buffered K/V, counted vmcnt(8), 2 barriers.
__launch_bounds__(256, 2)
__global__ void k_attn(const unsigned short* __restrict__ Qh,
                       const unsigned short* __restrict__ Kh,
                       const unsigned short* __restrict__ Vt,
                       unsigned short* __restrict__ O) {
    // pool: Ks[2][64][128] | Vts[2][128][64]  = 64 KB (epilogue reuses as Cs)
    __shared__ unsigned short pool[4 * 8192];

    const int t = threadIdx.x;
    const int w = t >> 6, lane = t & 63;
    const int lg = lane >> 4, lr = lane & 15;

    // block decode: s%8 = XCD = h>>1 (2 heads per XCD); batch pairing balances
    // per-CU work at 66 iters (heavy 31-qq first, light qq second).
    const int s = blockIdx.x & 255;
    const int batch = blockIdx.x >> 8;
    const int x = s & 7;
    const int hb = (s >> 3) & 1;
    const int h = x * 2 + hb;
    const int qq = s >> 4;
    const int qb = batch ? qq : (31 - qq);
    const int q0 = qb * 128;
    const int qbase = q0 + w * 32;   // this wave's first q-row

    // Q fragments in registers (wave's 32 queries x 128 d)
    bf16x8 qf[2][4];
    #pragma unroll
    for (int mi = 0; mi < 2; ++mi)
        #pragma unroll
        for (int kk = 0; kk < 4; ++kk)
            qf[mi][kk] = *(const bf16x8*)&Qh[((size_t)h * N_SEQ + qbase + mi * 16 + lr) * HD + kk * 32 + lg * 8];

    f32x4 acc[2][8];
    #pragma unroll
    for (int i = 0; i < 2; ++i)
        #pragma unroll
        for (int j = 0; j < 8; ++j) acc[i][j] = f32x4{0.f, 0.f, 0.f, 0.f};
    f32x4 accd[2];
    accd[0] = f32x4{0.f, 0.f, 0.f, 0.f};
    accd[1] = f32x4{0.f, 0.f, 0.f, 0.f};

    // ones B-fragment: row-sum lands in output col 0 (permutation-invariant)
    bf16x8 onesf;
    {
        short ov = (lr == 0) ? (short)0x3F80 : (short)0;
        #pragma unroll
        for (int j = 0; j < 8; ++j) onesf[j] = ov;
    }

    // staging geometry: K 1024 chunks (4/thread), V 1024 chunks (4/thread).
    // LDS linear dest (wave-uniform base + lane*16B); swizzle pre-applied to
    // the global source chunk index (involution), ds_read applies same XOR.
    int kch[4], vch[4];
    const unsigned short* kg[4];
    const unsigned short* vg[4];
    #pragma unroll
    for (int i = 0; i < 4; ++i) {
        int ch = i * 256 + t;
        kch[i] = ch;
        int r = ch >> 4, p = ch & 15;
        int csrc = (p & 8) | ((p ^ r) & 7);
        kg[i] = Kh + ((size_t)h * N_SEQ + r) * HD + csrc * 8;
    }
    #pragma unroll
    for (int i = 0; i < 4; ++i) {
        int ch = i * 256 + t;
        vch[i] = ch;
        int d = ch >> 3, p2 = ch & 7;       // d in [0,128), col chunk in [0,8)
        int c2src = (p2 ^ d) & 7;
        vg[i] = Vt + ((size_t)h * HD + d) * N_SEQ + c2src * 8;
    }

    const int nkb = 2 * qb + 2;

    // prologue: stage tile 0 into buf 0 (8 loads/thread)
    {
        #pragma unroll
        for (int i = 0; i < 4; ++i) { gll16(kg[i], pool + kch[i] * 8); kg[i] += 64 * HD; }
        #pragma unroll
        for (int i = 0; i < 4; ++i) { gll16(vg[i], pool + 16384 + vch[i] * 8); vg[i] += 64; }
    }

    union U8 { unsigned u[4]; bf16x8 v; };

    for (int kb = 0; kb < nkb; ++kb) {
        const int cur = kb & 1;
        const int k0 = kb * 64;

        if (kb + 1 < nkb) {
            const int nxt = cur ^ 1;
            unsigned short* Kn = pool + nxt * 8192;
            unsigned short* Vn = pool + 16384 + nxt * 8192;
            #pragma unroll
            for (int i = 0; i < 4; ++i) { gll16(kg[i], Kn + kch[i] * 8); kg[i] += 64 * HD; }
            #pragma unroll
            for (int i = 0; i < 4; ++i) { gll16(vg[i], Vn + vch[i] * 8); vg[i] += 64; }
            asm volatile("s_waitcnt vmcnt(8)" ::: "memory");   // tile kb's 8 landed
        } else {
            asm volatile("s_waitcnt vmcnt(0)" ::: "memory");
        }
        __builtin_amdgcn_s_barrier();   // buf[cur] ready for all waves

        const unsigned short* Kc = pool + cur * 8192;
        const unsigned short* Vc = pool + 16384 + cur * 8192;

        // ---- S^T = K Q^T (swapped): lane holds S[k = 16nj+4lg+r][q = 16mi+lr]
        f32x4 sa[2][4];
        #pragma unroll
        for (int i = 0; i < 2; ++i)
            #pragma unroll
            for (int j = 0; j < 4; ++j) sa[i][j] = f32x4{0.f, 0.f, 0.f, 0.f};
        #pragma unroll
        for (int nn = 0; nn < 2; ++nn) {
            bf16x8 kf[2][4];
            #pragma unroll
            for (int nj = 0; nj < 2; ++nj)
                #pragma unroll
                for (int kk = 0; kk < 4; ++kk) {
                    int row = (nn * 2 + nj) * 16 + lr;
                    int c = kk * 4 + lg;
                    int cs = (c & 8) | ((c ^ row) & 7);
                    kf[nj][kk] = *(const bf16x8*)&Kc[row * 128 + cs * 8];
                }
            __builtin_amdgcn_s_setprio(1);
            #pragma unroll
            for (int kk = 0; kk < 4; ++kk)
                #pragma unroll
                for (int nj = 0; nj < 2; ++nj)
                    #pragma unroll
                    for (int mi = 0; mi < 2; ++mi)
                        sa[mi][nn * 2 + nj] = __builtin_amdgcn_mfma_f32_16x16x32_bf16(
                            kf[nj][kk], qf[mi][kk], sa[mi][nn * 2 + nj], 0, 0, 0);
            __builtin_amdgcn_s_setprio(0);
        }

        // ---- mask + ^4 + pack to bf16 pairs, all in registers.
        // word w[mi][nj][j] = bf16pair(p[2j], p[2j+1]) for k = k0+16nj+4lg+{2j,2j+1}
        unsigned wreg[2][4][2];
        const bool nomask = (k0 + 63 <= qbase);
        #pragma unroll
        for (int mi = 0; mi < 2; ++mi)
            #pragma unroll
            for (int nj = 0; nj < 4; ++nj) {
                float p[4];
                #pragma unroll
                for (int r = 0; r < 4; ++r) {
                    float sv = sa[mi][nj][r];
                    float t2 = sv * sv;
                    p[r] = t2 * t2;
                    if (!nomask) {
                        int gk = k0 + nj * 16 + lg * 4 + r;
                        int gq = qbase + mi * 16 + lr;
                        p[r] = (gk <= gq) ? p[r] : 0.0f;
                    }
                }
                asm("v_cvt_pk_bf16_f32 %0, %1, %2" : "=v"(wreg[mi][nj][0]) : "v"(p[0]), "v"(p[1]));
                asm("v_cvt_pk_bf16_f32 %0, %1, %2" : "=v"(wreg[mi][nj][1]) : "v"(p[2]), "v"(p[3]));
            }

        // ---- O += P V, denom += P * ones.  Virtual-k A-frag: lane(lr,lg)
        // slot j -> actual k = 32*s2 + 4*lg + j (j<4) | 32*s2+16+4*lg+(j-4).
        // V read replicates sigma: two b64 at chunks (s2*4+(lg>>1)) and (+2).
        #pragma unroll
        for (int s2 = 0; s2 < 2; ++s2) {
            bf16x8 pa[2];
            #pragma unroll
            for (int mi = 0; mi < 2; ++mi) {
                U8 u;
                u.u[0] = wreg[mi][2 * s2][0];
                u.u[1] = wreg[mi][2 * s2][1];
                u.u[2] = wreg[mi][2 * s2 + 1][0];
                u.u[3] = wreg[mi][2 * s2 + 1][1];
                pa[mi] = u.v;
            }
            __builtin_amdgcn_s_setprio(1);
            #pragma unroll
            for (int ni = 0; ni < 8; ++ni) {
                int d = ni * 16 + lr;
                int base = d * 64 + (lg & 1) * 4;
                int cA = ((s2 * 4 + (lg >> 1)) ^ d) & 7;
                int cB = ((s2 * 4 + 2 + (lg >> 1)) ^ d) & 7;
                uint2 va = *(const uint2*)&Vc[base + cA * 8];
                uint2 vb = *(const uint2*)&Vc[base + cB * 8];
                U8 tv;
                tv.u[0] = va.x; tv.u[1] = va.y; tv.u[2] = vb.x; tv.u[3] = vb.y;
                #pragma unroll
                for (int mi = 0; mi < 2; ++mi)
                    acc[mi][ni] = __builtin_amdgcn_mfma_f32_16x16x32_bf16(pa[mi], tv.v, acc[mi][ni], 0, 0, 0);
            }
            #pragma unroll
            for (int mi = 0; mi < 2; ++mi)
                accd[mi] = __builtin_amdgcn_mfma_f32_16x16x32_bf16(pa[mi], onesf, accd[mi], 0, 0, 0);
            __builtin_amdgcn_s_setprio(0);
        }

        __builtin_amdgcn_s_barrier();   // all waves done reading buf[cur]
    }

    // epilogue: out = acc / denom, staged via LDS (overlays K/V bufs)
    unsigned short* Cs = pool;   // [128][128] = 32 KB
    #pragma unroll
    for (int mi = 0; mi < 2; ++mi) {
        #pragma unroll
        for (int r = 0; r < 4; ++r) {
            float dv = __shfl(accd[mi][r], lane & 48);  // col 0 lives in lane lg*16
            float rinv = 1.0f / dv;
            int rw = w * 32 + mi * 16 + lg * 4 + r;
            #pragma unroll
            for (int ni = 0; ni < 8; ++ni)
                Cs[rw * 128 + ni * 16 + lr] = f2bf(acc[mi][ni][r] * rinv);
        }
    }
    __syncthreads();
    #pragma unroll
    for (int i = 0; i < 8; ++i) {
        int ch = i * 256 + t;
        int row = ch >> 4, c8 = (ch & 15) * 8;
        *(uint4*)&O[(size_t)(q0 + row) * EDIM + h * HD + c8] = *(const uint4*)&Cs[row * 128 + c8];
    }
}

// ---------------------------------------------------------------- launch
extern "C" void kernel_launch(void* const* d_in, const int* in_sizes, int n_in,
                              void* d_out, int out_size, void* d_ws, size_t ws_size,
                              hipStream_t stream) {
    const float* x        = (const float*)d_in[0];
    const float* w_qkv    = (const float*)d_in[1];
    const float* w_out    = (const float*)d_in[2];
    const float* ln_scale = (const float*)d_in[3];
    const float* ln_bias  = (const float*)d_in[4];

    if (ws_size < 134217728u) return;  // need 128 MiB

    char* ws = (char*)d_ws;
    unsigned short* xb    = (unsigned short*)(ws);              // 16 MiB; reused as attnO
    unsigned short* wqkvT = (unsigned short*)(ws + 16777216);   // 24 MiB; reused as Qh
    unsigned short* woutT = (unsigned short*)(ws + 41943040);   //  8 MiB
    unsigned short* proj  = (unsigned short*)(ws + 50331648);   // 48 MiB
    unsigned short* Kh    = (unsigned short*)(ws + 100663296);  // 16 MiB
    unsigned short* Vt    = (unsigned short*)(ws + 117440512);  // 16 MiB
    unsigned short* Qh    = wqkvT;   // alias: w_qkvT dead after GEMM1
    unsigned short* attnO = xb;      // alias: xb dead after GEMM1

    k_convert_x<<<2048, 256, 0, stream>>>(x, xb, (N_SEQ * EDIM) / 4);
    k_transpose_f32_bf16<<<dim3(3 * EDIM / 64, EDIM / 64), 256, 0, stream>>>(w_qkv, wqkvT, EDIM, 3 * EDIM);
    k_transpose_f32_bf16<<<dim3(EDIM / 64, EDIM / 64), 256, 0, stream>>>(w_out, woutT, EDIM, EDIM);
    k_gemm_bt<0><<<dim3(3 * EDIM / 128, N_SEQ / 128), 256, 0, stream>>>(xb, wqkvT, proj, N_SEQ, 3 * EDIM, EDIM);
    k_ropeln<<<N_SEQ, 256, 0, stream>>>(proj, ln_scale, ln_bias, Qh, Kh);
    k_vtrans<<<dim3(N_SEQ / 64, NH), 256, 0, stream>>>(proj, Vt);
    k_attn<<<512, 256, 0, stream>>>(Qh, Kh, Vt, attnO);
    k_gemm_bt<1><<<dim3(EDIM / 128, N_SEQ / 128), 256, 0, stream>>>(attnO, woutT, (float*)d_out, N_SEQ, EDIM, EDIM);
}

// Round 8
// 305.407 us; speedup vs baseline: 1.8025x; 1.0243x over previous
//
#include <hip/hip_runtime.h>
#include <stdint.h>
#include <math.h>

// Problem constants
#define N_SEQ 4096
#define EDIM  2048
#define NH    16
#define HD    128

typedef __attribute__((ext_vector_type(8))) short bf16x8;
typedef __attribute__((ext_vector_type(4))) float f32x4;

#define AS1 __attribute__((address_space(1)))
#define AS3 __attribute__((address_space(3)))

__device__ __forceinline__ void gll16(const unsigned short* g, unsigned short* l) {
    __builtin_amdgcn_global_load_lds((const AS1 unsigned int*)g,
                                     (AS3 unsigned int*)l, 16, 0, 0);
}

__device__ __forceinline__ unsigned short f2bf(float f) {
    union { float f; unsigned u; } v; v.f = f;
    unsigned r = v.u + 0x7FFFu + ((v.u >> 16) & 1u);
    return (unsigned short)(r >> 16);
}
__device__ __forceinline__ float bf2f(unsigned short h) {
    union { unsigned u; float f; } v; v.u = ((unsigned)h) << 16;
    return v.f;
}

// ---------------------------------------------------------------- convert x
__global__ void k_convert_x(const float* __restrict__ x,
                            unsigned short* __restrict__ xb, int n4) {
    int i = blockIdx.x * blockDim.x + threadIdx.x;
    int stride = gridDim.x * blockDim.x;
    for (; i < n4; i += stride) {
        float4 v = ((const float4*)x)[i];
        ushort4 o;
        o.x = f2bf(v.x); o.y = f2bf(v.y); o.z = f2bf(v.z); o.w = f2bf(v.w);
        ((ushort4*)xb)[i] = o;
    }
}

// ---------------------------------------------- transpose f32 (RxC) -> bf16 (CxR)
__global__ void k_transpose_f32_bf16(const float* __restrict__ in,
                                     unsigned short* __restrict__ out,
                                     int R, int C) {
    __shared__ unsigned short Ls[64][68];
    const int c0 = blockIdx.x * 64, r0 = blockIdx.y * 64;
    const int t = threadIdx.x;
    #pragma unroll
    for (int i = 0; i < 4; ++i) {
        int ch = i * 256 + t;              // 1024 float4 chunks
        int r = ch >> 4, c4 = (ch & 15) * 4;
        float4 v = *(const float4*)&in[(size_t)(r0 + r) * C + c0 + c4];
        ushort4 o;
        o.x = f2bf(v.x); o.y = f2bf(v.y); o.z = f2bf(v.z); o.w = f2bf(v.w);
        *(ushort4*)&Ls[r][c4] = o;
    }
    __syncthreads();
    #pragma unroll
    for (int i = 0; i < 2; ++i) {
        int ch = i * 256 + t;              // 512 chunks of 8 bf16
        int rr = ch >> 3, c8 = (ch & 7) * 8;
        unsigned short vals[8];
        #pragma unroll
        for (int j = 0; j < 8; ++j) vals[j] = Ls[c8 + j][rr];
        uint4 pk;
        pk.x = (unsigned)vals[0] | ((unsigned)vals[1] << 16);
        pk.y = (unsigned)vals[2] | ((unsigned)vals[3] << 16);
        pk.z = (unsigned)vals[4] | ((unsigned)vals[5] << 16);
        pk.w = (unsigned)vals[6] | ((unsigned)vals[7] << 16);
        *(uint4*)&out[(size_t)(c0 + rr) * R + r0 + c8] = pk;
    }
}

// ---------------------------------------------------------------- bt GEMM
// C[M,N] = A[M,K] * Bt[N,K]^T  (bf16 in, f32 acc, bf16 or f32 out)
template<int F32OUT>
__launch_bounds__(256, 2)
__global__ void k_gemm_bt(const unsigned short* __restrict__ A,
                          const unsigned short* __restrict__ Bt,
                          void* __restrict__ C,
                          int M, int N, int K) {
    __shared__ unsigned short sh[2 * 128 * 64];   // As | Bs, linear [128][64]
    unsigned short* As = sh;
    unsigned short* Bs = sh + 128 * 64;

    const int t = threadIdx.x;
    const int wave = t >> 6, lane = t & 63;
    const int wm = wave >> 1, wn = wave & 1;
    const int lg = lane >> 4, lr = lane & 15;

    // XCD-aware bijective swizzle (nwg % 8 == 0 for all our grids)
    const int nbx = gridDim.x;
    const int nwg = nbx * gridDim.y;
    int bid = blockIdx.y * nbx + blockIdx.x;
    int swz = (bid & 7) * (nwg >> 3) + (bid >> 3);
    const int m0 = (swz / nbx) * 128;
    const int n0 = (swz % nbx) * 128;

    const unsigned short* aptr = A  + (size_t)m0 * K;
    const unsigned short* bptr = Bt + (size_t)n0 * K;

    f32x4 acc[4][4];
    #pragma unroll
    for (int i = 0; i < 4; ++i)
        #pragma unroll
        for (int j = 0; j < 4; ++j) acc[i][j] = f32x4{0.f, 0.f, 0.f, 0.f};

    // per-thread staging geometry (loop-invariant)
    int schr[4], srow[4], scb[4];
    #pragma unroll
    for (int i = 0; i < 4; ++i) {
        int ch = (i * 4 + wave) * 64 + lane;   // 0..1023, wave-uniform base + lane
        schr[i] = ch;
        srow[i] = ch >> 3;
        scb[i]  = (ch & 7) ^ ((ch >> 3) & 7);  // inverse-swizzled source col-block
    }

    const int nkb = K >> 6;
    for (int kb = 0; kb < nkb; ++kb) {
        __syncthreads();   // previous iter's ds_reads done before overwrite
        #pragma unroll
        for (int i = 0; i < 4; ++i) {
            const size_t goff = (size_t)srow[i] * K + (size_t)kb * 64 + scb[i] * 8;
            gll16(&aptr[goff], &As[schr[i] * 8]);
            gll16(&bptr[goff], &Bs[schr[i] * 8]);
        }
        __syncthreads();   // drains vmcnt+lgkm (compiler-inserted before barrier)

        #pragma unroll
        for (int kk = 0; kk < 2; ++kk) {
            bf16x8 af[4], bf[4];
            const int cbx = ((kk * 4 + lg) ^ (lr & 7)) * 8;  // swizzled read col
            #pragma unroll
            for (int i = 0; i < 4; ++i) {
                af[i] = *(const bf16x8*)&As[(wm * 64 + i * 16 + lr) * 64 + cbx];
                bf[i] = *(const bf16x8*)&Bs[(wn * 64 + i * 16 + lr) * 64 + cbx];
            }
            #pragma unroll
            for (int i = 0; i < 4; ++i)
                #pragma unroll
                for (int j = 0; j < 4; ++j)
                    acc[i][j] = __builtin_amdgcn_mfma_f32_16x16x32_bf16(af[i], bf[j], acc[i][j], 0, 0, 0);
        }
    }

    if (F32OUT) {
        #pragma unroll
        for (int i = 0; i < 4; ++i) {
            int row0 = m0 + wm * 64 + i * 16 + lg * 4;
            #pragma unroll
            for (int j = 0; j < 4; ++j) {
                int col = n0 + wn * 64 + j * 16 + lr;
                #pragma unroll
                for (int r = 0; r < 4; ++r)
                    ((float*)C)[(size_t)(row0 + r) * N + col] = acc[i][j][r];
            }
        }
    } else {
        // stage bf16 C-tile in LDS, write out coalesced uint4 rows
        __syncthreads();
        unsigned short* Cs = sh;     // [128][128]
        #pragma unroll
        for (int i = 0; i < 4; ++i) {
            #pragma unroll
            for (int j = 0; j < 4; ++j) {
                int col = wn * 64 + j * 16 + lr;
                #pragma unroll
                for (int r = 0; r < 4; ++r)
                    Cs[(wm * 64 + i * 16 + lg * 4 + r) * 128 + col] = f2bf(acc[i][j][r]);
            }
        }
        __syncthreads();
        #pragma unroll
        for (int i = 0; i < 8; ++i) {
            int ch = i * 256 + t;             // 2048 chunks of 8 shorts
            int row = ch >> 4, c8 = (ch & 15) * 8;
            *(uint4*)&((unsigned short*)C)[(size_t)(m0 + row) * N + n0 + c8] =
                *(const uint4*)&Cs[row * 128 + c8];
        }
    }
}

// ------------------------------------------------------- RoPE + LayerNorm (q,k)
__global__ void k_ropeln(const unsigned short* __restrict__ proj,
                         const float* __restrict__ ln_scale,
                         const float* __restrict__ ln_bias,
                         unsigned short* __restrict__ Qh,
                         unsigned short* __restrict__ Kh) {
    const int n = blockIdx.x;
    const int wave = threadIdx.x >> 6, lane = threadIdx.x & 63;
    float inv = expf(-((float)(2 * lane) / 128.0f) * 9.210340371976184f);
    float ang = (float)n * inv;
    float c = cosf(ang), s = sinf(ang);
    const float sc1 = ln_scale[lane], sc2 = ln_scale[lane + 64];
    const float b1 = ln_bias[lane],  b2 = ln_bias[lane + 64];

    for (int r = wave; r < 32; r += 4) {
        int h = r >> 1, qk = r & 1;
        const unsigned short* src = proj + (size_t)n * (3 * EDIM) + qk * EDIM + h * HD;
        float x1 = bf2f(src[lane]), x2 = bf2f(src[lane + 64]);
        float o1 = x1 * c - x2 * s;
        float o2 = x1 * s + x2 * c;
        float sum = o1 + o2, sq = o1 * o1 + o2 * o2;
        #pragma unroll
        for (int d = 1; d < 64; d <<= 1) {
            sum += __shfl_xor(sum, d);
            sq  += __shfl_xor(sq, d);
        }
        float mean = sum * (1.0f / 128.0f);
        float var = sq * (1.0f / 128.0f) - mean * mean;
        float rstd = rsqrtf(var + 1e-5f);
        float y1 = (o1 - mean) * rstd * sc1 + b1;
        float y2 = (o2 - mean) * rstd * sc2 + b2;
        unsigned short* dst = (qk ? Kh : Qh) + ((size_t)h * N_SEQ + n) * HD;
        dst[lane]      = f2bf(y1);
        dst[lane + 64] = f2bf(y2);
    }
}

// ---------------------------------------------------- V transpose: [n][d] -> [d][n]
// Writes Vt with the PV k-permutation baked into each 64-key tile:
// tile position p*8+i  <-  k = 32*(p>>2) + 16*(i>>2) + 4*(p&3) + (i&3)
// so attn's V B-fragment (s2,lg) is ONE contiguous b128 chunk c = s2*4+lg.
__global__ void k_vtrans(const unsigned short* __restrict__ proj,
                         unsigned short* __restrict__ Vt) {
    __shared__ unsigned short Ls[64][136];
    const int h = blockIdx.y;
    const int n0 = blockIdx.x * 64;
    const int t = threadIdx.x;
    #pragma unroll
    for (int i = 0; i < 4; ++i) {
        int ch = i * 256 + t;
        int r = ch >> 4, d0 = (ch & 15) * 8;
        uint4 v = *(const uint4*)&proj[(size_t)(n0 + r) * (3 * EDIM) + 2 * EDIM + h * HD + d0];
        *(uint4*)&Ls[r][d0] = v;
    }
    __syncthreads();
    #pragma unroll
    for (int i = 0; i < 4; ++i) {
        int ch = i * 256 + t;
        int d = ch >> 3, p = ch & 7;
        unsigned short vals[8];
        #pragma unroll
        for (int j = 0; j < 8; ++j) {
            int ko = 32 * (p >> 2) + 16 * (j >> 2) + 4 * (p & 3) + (j & 3);
            vals[j] = Ls[ko][d];
        }
        uint4 pk;
        pk.x = (unsigned)vals[0] | ((unsigned)vals[1] << 16);
        pk.y = (unsigned)vals[2] | ((unsigned)vals[3] << 16);
        pk.z = (unsigned)vals[4] | ((unsigned)vals[5] << 16);
        pk.w = (unsigned)vals[6] | ((unsigned)vals[7] << 16);
        *(uint4*)&Vt[((size_t)h * HD + d) * N_SEQ + n0 + p * 8] = pk;
    }
}

// ------------------------------------------------------- polynomial attention
// Qh,Kh: [NH][N_SEQ][HD], Vt: [NH][HD][N_SEQ] (k-permuted tiles). O: [N_SEQ][EDIM].
// v7: swapped QK^T keeps P in registers (cvt_pk into PV A-frags); V B-frag is
// a single swizzled ds_read_b128 (2-way, free) thanks to the permuted Vt
// layout; manual unroll-2 makes buffer bases compile-time so all LDS
// addressing is loop-invariant. global_load_lds dbuf staging, vmcnt(8).
__launch_bounds__(256, 2)
__global__ void k_attn(const unsigned short* __restrict__ Qh,
                       const unsigned short* __restrict__ Kh,
                       const unsigned short* __restrict__ Vt,
                       unsigned short* __restrict__ O) {
    // pool: Ks[2][64][128] | Vts[2][128][64]  = 64 KB (epilogue reuses as Cs)
    __shared__ unsigned short pool[4 * 8192];

    const int t = threadIdx.x;
    const int w = t >> 6, lane = t & 63;
    const int lg = lane >> 4, lr = lane & 15;

    // block decode: s%8 = XCD = h>>1 (2 heads per XCD); batch pairing balances
    // per-CU work at 66 iters (heavy 31-qq first, light qq second).
    const int s = blockIdx.x & 255;
    const int batch = blockIdx.x >> 8;
    const int x = s & 7;
    const int hb = (s >> 3) & 1;
    const int h = x * 2 + hb;
    const int qq = s >> 4;
    const int qb = batch ? qq : (31 - qq);
    const int q0 = qb * 128;
    const int qbase = q0 + w * 32;   // this wave's first q-row

    // Q fragments in registers (wave's 32 queries x 128 d)
    bf16x8 qf[2][4];
    #pragma unroll
    for (int mi = 0; mi < 2; ++mi)
        #pragma unroll
        for (int kk = 0; kk < 4; ++kk)
            qf[mi][kk] = *(const bf16x8*)&Qh[((size_t)h * N_SEQ + qbase + mi * 16 + lr) * HD + kk * 32 + lg * 8];

    f32x4 acc[2][8];
    #pragma unroll
    for (int i = 0; i < 2; ++i)
        #pragma unroll
        for (int j = 0; j < 8; ++j) acc[i][j] = f32x4{0.f, 0.f, 0.f, 0.f};
    f32x4 accd[2];
    accd[0] = f32x4{0.f, 0.f, 0.f, 0.f};
    accd[1] = f32x4{0.f, 0.f, 0.f, 0.f};

    // ones B-fragment: row-sum lands in output col 0 (k-permutation-invariant)
    bf16x8 onesf;
    {
        short ov = (lr == 0) ? (short)0x3F80 : (short)0;
        #pragma unroll
        for (int j = 0; j < 8; ++j) onesf[j] = ov;
    }

    // staging geometry: K 1024 chunks (4/thread), V 1024 chunks (4/thread).
    // LDS linear dest (wave-uniform base + lane*16B); swizzle pre-applied to
    // the global source chunk index (involution), ds_read applies same XOR.
    int kch[4], vch[4];
    const unsigned short* kg[4];
    const unsigned short* vg[4];
    #pragma unroll
    for (int i = 0; i < 4; ++i) {
        int ch = i * 256 + t;
        kch[i] = ch;
        int r = ch >> 4, p = ch & 15;
        int csrc = (p & 8) | ((p ^ r) & 7);
        kg[i] = Kh + ((size_t)h * N_SEQ + r) * HD + csrc * 8;
    }
    #pragma unroll
    for (int i = 0; i < 4; ++i) {
        int ch = i * 256 + t;
        vch[i] = ch;
        int d = ch >> 3, p2 = ch & 7;       // d in [0,128), col chunk in [0,8)
        int c2src = (p2 ^ d) & 7;
        vg[i] = Vt + ((size_t)h * HD + d) * N_SEQ + c2src * 8;
    }

    const int nkb = 2 * qb + 2;   // always even

    union U8 { unsigned u[4]; bf16x8 v; };

    auto stage = [&](unsigned short* Kn, unsigned short* Vn) {
        #pragma unroll
        for (int i = 0; i < 4; ++i) { gll16(kg[i], Kn + kch[i] * 8); kg[i] += 64 * HD; }
        #pragma unroll
        for (int i = 0; i < 4; ++i) { gll16(vg[i], Vn + vch[i] * 8); vg[i] += 64; }
    };

    auto compute = [&](int k0, const unsigned short* Kc, const unsigned short* Vc) {
        // ---- S^T = K Q^T (swapped): lane holds S[k = 16nj+4lg+r][q = 16mi+lr]
        f32x4 sa[2][4];
        #pragma unroll
        for (int i = 0; i < 2; ++i)
            #pragma unroll
            for (int j = 0; j < 4; ++j) sa[i][j] = f32x4{0.f, 0.f, 0.f, 0.f};
        #pragma unroll
        for (int nn = 0; nn < 2; ++nn) {
            bf16x8 kf[2][4];
            #pragma unroll
            for (int nj = 0; nj < 2; ++nj)
                #pragma unroll
                for (int kk = 0; kk < 4; ++kk) {
                    int row = (nn * 2 + nj) * 16 + lr;
                    int c = kk * 4 + lg;
                    int cs = (c & 8) | ((c ^ row) & 7);
                    kf[nj][kk] = *(const bf16x8*)&Kc[row * 128 + cs * 8];
                }
            __builtin_amdgcn_s_setprio(1);
            #pragma unroll
            for (int kk = 0; kk < 4; ++kk)
                #pragma unroll
                for (int nj = 0; nj < 2; ++nj)
                    #pragma unroll
                    for (int mi = 0; mi < 2; ++mi)
                        sa[mi][nn * 2 + nj] = __builtin_amdgcn_mfma_f32_16x16x32_bf16(
                            kf[nj][kk], qf[mi][kk], sa[mi][nn * 2 + nj], 0, 0, 0);
            __builtin_amdgcn_s_setprio(0);
        }

        // ---- mask + ^4 + pack to bf16 pairs, all in registers.
        unsigned wreg[2][4][2];
        const bool nomask = (k0 + 63 <= qbase);
        #pragma unroll
        for (int mi = 0; mi < 2; ++mi)
            #pragma unroll
            for (int nj = 0; nj < 4; ++nj) {
                float p[4];
                #pragma unroll
                for (int r = 0; r < 4; ++r) {
                    float sv = sa[mi][nj][r];
                    float t2 = sv * sv;
                    p[r] = t2 * t2;
                    if (!nomask) {
                        int gk = k0 + nj * 16 + lg * 4 + r;
                        int gq = qbase + mi * 16 + lr;
                        p[r] = (gk <= gq) ? p[r] : 0.0f;
                    }
                }
                asm("v_cvt_pk_bf16_f32 %0, %1, %2" : "=v"(wreg[mi][nj][0]) : "v"(p[0]), "v"(p[1]));
                asm("v_cvt_pk_bf16_f32 %0, %1, %2" : "=v"(wreg[mi][nj][1]) : "v"(p[2]), "v"(p[3]));
            }

        // ---- O += P V, denom += P * ones.  A-frag slot j (fragment s2) holds
        // k = 32*s2 + 16*(j>>2) + 4*lg + (j&3); Vt's tile permutation puts
        // exactly those k at chunk c = s2*4+lg -> one b128 per (ni,s2).
        #pragma unroll
        for (int s2 = 0; s2 < 2; ++s2) {
            bf16x8 pa[2];
            #pragma unroll
            for (int mi = 0; mi < 2; ++mi) {
                U8 u;
                u.u[0] = wreg[mi][2 * s2][0];
                u.u[1] = wreg[mi][2 * s2][1];
                u.u[2] = wreg[mi][2 * s2 + 1][0];
                u.u[3] = wreg[mi][2 * s2 + 1][1];
                pa[mi] = u.v;
            }
            __builtin_amdgcn_s_setprio(1);
            #pragma unroll
            for (int ni = 0; ni < 8; ++ni) {
                int d = ni * 16 + lr;
                int cs = ((s2 * 4 + lg) ^ (d & 7)) & 7;
                bf16x8 vf = *(const bf16x8*)&Vc[d * 64 + cs * 8];
                #pragma unroll
                for (int mi = 0; mi < 2; ++mi)
                    acc[mi][ni] = __builtin_amdgcn_mfma_f32_16x16x32_bf16(pa[mi], vf, acc[mi][ni], 0, 0, 0);
            }
            #pragma unroll
            for (int mi = 0; mi < 2; ++mi)
                accd[mi] = __builtin_amdgcn_mfma_f32_16x16x32_bf16(pa[mi], onesf, accd[mi], 0, 0, 0);
            __builtin_amdgcn_s_setprio(0);
        }
    };

    // prologue: stage tile 0 into buf 0 (8 loads/thread)
    stage(pool, pool + 16384);

    for (int kb = 0; kb < nkb; kb += 2) {
        // ---- A: prefetch tile kb+1 -> buf1, compute tile kb from buf0
        stage(pool + 8192, pool + 16384 + 8192);
        asm volatile("s_waitcnt vmcnt(8)" ::: "memory");
        __builtin_amdgcn_s_barrier();
        compute(kb * 64, pool, pool + 16384);
        __builtin_amdgcn_s_barrier();
        // ---- B: prefetch tile kb+2 -> buf0 (unless last), compute tile kb+1
        if (kb + 2 < nkb) {
            stage(pool, pool + 16384);
            asm volatile("s_waitcnt vmcnt(8)" ::: "memory");
        } else {
            asm volatile("s_waitcnt vmcnt(0)" ::: "memory");
        }
        __builtin_amdgcn_s_barrier();
        compute((kb + 1) * 64, pool + 8192, pool + 16384 + 8192);
        __builtin_amdgcn_s_barrier();
    }

    // epilogue: out = acc / denom, staged via LDS (overlays K/V bufs)
    unsigned short* Cs = pool;   // [128][128] = 32 KB
    #pragma unroll
    for (int mi = 0; mi < 2; ++mi) {
        #pragma unroll
        for (int r = 0; r < 4; ++r) {
            float dv = __shfl(accd[mi][r], lane & 48);  // col 0 lives in lane lg*16
            float rinv = 1.0f / dv;
            int rw = w * 32 + mi * 16 + lg * 4 + r;
            #pragma unroll
            for (int ni = 0; ni < 8; ++ni)
                Cs[rw * 128 + ni * 16 + lr] = f2bf(acc[mi][ni][r] * rinv);
        }
    }
    __syncthreads();
    #pragma unroll
    for (int i = 0; i < 8; ++i) {
        int ch = i * 256 + t;
        int row = ch >> 4, c8 = (ch & 15) * 8;
        *(uint4*)&O[(size_t)(q0 + row) * EDIM + h * HD + c8] = *(const uint4*)&Cs[row * 128 + c8];
    }
}

// ---------------------------------------------------------------- launch
extern "C" void kernel_launch(void* const* d_in, const int* in_sizes, int n_in,
                              void* d_out, int out_size, void* d_ws, size_t ws_size,
                              hipStream_t stream) {
    const float* x        = (const float*)d_in[0];
    const float* w_qkv    = (const float*)d_in[1];
    const float* w_out    = (const float*)d_in[2];
    const float* ln_scale = (const float*)d_in[3];
    const float* ln_bias  = (const float*)d_in[4];

    if (ws_size < 134217728u) return;  // need 128 MiB

    char* ws = (char*)d_ws;
    unsigned short* xb    = (unsigned short*)(ws);              // 16 MiB; reused as attnO
    unsigned short* wqkvT = (unsigned short*)(ws + 16777216);   // 24 MiB; reused as Qh
    unsigned short* woutT = (unsigned short*)(ws + 41943040);   //  8 MiB
    unsigned short* proj  = (unsigned short*)(ws + 50331648);   // 48 MiB
    unsigned short* Kh    = (unsigned short*)(ws + 100663296);  // 16 MiB
    unsigned short* Vt    = (unsigned short*)(ws + 117440512);  // 16 MiB
    unsigned short* Qh    = wqkvT;   // alias: w_qkvT dead after GEMM1
    unsigned short* attnO = xb;      // alias: xb dead after GEMM1

    k_convert_x<<<2048, 256, 0, stream>>>(x, xb, (N_SEQ * EDIM) / 4);
    k_transpose_f32_bf16<<<dim3(3 * EDIM / 64, EDIM / 64), 256, 0, stream>>>(w_qkv, wqkvT, EDIM, 3 * EDIM);
    k_transpose_f32_bf16<<<dim3(EDIM / 64, EDIM / 64), 256, 0, stream>>>(w_out, woutT, EDIM, EDIM);
    k_gemm_bt<0><<<dim3(3 * EDIM / 128, N_SEQ / 128), 256, 0, stream>>>(xb, wqkvT, proj, N_SEQ, 3 * EDIM, EDIM);
    k_ropeln<<<N_SEQ, 256, 0, stream>>>(proj, ln_scale, ln_bias, Qh, Kh);
    k_vtrans<<<dim3(N_SEQ / 64, NH), 256, 0, stream>>>(proj, Vt);
    k_attn<<<512, 256, 0, stream>>>(Qh, Kh, Vt, attnO);
    k_gemm_bt<1><<<dim3(EDIM / 128, N_SEQ / 128), 256, 0, stream>>>(attnO, woutT, (float*)d_out, N_SEQ, EDIM, EDIM);
}